// Round 1
// baseline (3128.774 us; speedup 1.0000x reference)
//
#include <hip/hip_runtime.h>

// ConvSNN forward: T=16, B=128. All fp32.
// LIF: v_dec = v + 0.1*(i - v); i_dec = 0.8*i; z = (v_dec > vth); v' = z?0:v_dec; i' = i_dec + inp
// LI : v' = v + 0.1*(i - v); i' = 0.8*i + inp

__device__ __forceinline__ float lif1(float inp, float vth, float& v, float& i) {
  float vd = fmaf(0.1f, i - v, v);
  float z = (vd > vth) ? 1.0f : 0.0f;
  v = (vd > vth) ? 0.0f : vd;
  i = fmaf(0.8f, i, inp);
  return z;
}

// ---------------- conv1 (3->32) @32x32 + LIF(0.25) + pool -> z1p (B,32,16,16)
// grid: B*2 blocks (16 oc each), 256 threads = 16x16 pooled positions
__global__ __launch_bounds__(256) void k_conv1(const float* __restrict__ x,
    const float* __restrict__ wc, float4* __restrict__ s1v, float4* __restrict__ s1i,
    float* __restrict__ z1p)
{
  const int b = blockIdx.x >> 1;
  const int g = blockIdx.x & 1;
  const int tid = threadIdx.x;
  __shared__ float xs[3][34][34];
  __shared__ float wl[16 * 27];
  for (int idx = tid; idx < 16 * 27; idx += 256) wl[idx] = wc[g * (16 * 27) + idx];
  for (int idx = tid; idx < 3 * 34 * 34; idx += 256) {
    int c = idx / 1156, r = idx % 1156;
    int hh = r / 34, ww = r % 34;
    float v = 0.0f;
    if (hh >= 1 && hh <= 32 && ww >= 1 && ww <= 32)
      v = x[((b * 3 + c) * 32 + (hh - 1)) * 32 + (ww - 1)];
    xs[c][hh][ww] = v;
  }
  __syncthreads();
  const int ph = tid >> 4, pw = tid & 15;
  float p[3][4][4];
#pragma unroll
  for (int c = 0; c < 3; ++c)
#pragma unroll
    for (int r = 0; r < 4; ++r)
#pragma unroll
      for (int cc = 0; cc < 4; ++cc)
        p[c][r][cc] = xs[c][2 * ph + r][2 * pw + cc];

  for (int j = 0; j < 16; ++j) {
    float s00 = 0, s01 = 0, s10 = 0, s11 = 0;
    const float* w = &wl[j * 27];
#pragma unroll
    for (int c = 0; c < 3; ++c)
#pragma unroll
      for (int kh = 0; kh < 3; ++kh)
#pragma unroll
        for (int kw = 0; kw < 3; ++kw) {
          const float wv = w[(c * 3 + kh) * 3 + kw];
          s00 = fmaf(p[c][kh][kw],         wv, s00);
          s01 = fmaf(p[c][kh][kw + 1],     wv, s01);
          s10 = fmaf(p[c][kh + 1][kw],     wv, s10);
          s11 = fmaf(p[c][kh + 1][kw + 1], wv, s11);
        }
    const int oc = g * 16 + j;
    const int sidx = ((b * 32 + oc) * 16 + ph) * 16 + pw;
    float4 v4 = s1v[sidx], i4 = s1i[sidx];
    float z0 = lif1(s00, 0.25f, v4.x, i4.x);
    float z1 = lif1(s01, 0.25f, v4.y, i4.y);
    float z2 = lif1(s10, 0.25f, v4.z, i4.z);
    float z3 = lif1(s11, 0.25f, v4.w, i4.w);
    s1v[sidx] = v4; s1i[sidx] = i4;
    z1p[sidx] = 0.25f * (z0 + z1 + z2 + z3);
  }
}

// ---------------- conv2 (32->64) @16x16 + LIF(0.2) + pool -> z2p (B,64,8,8)
// grid: B*4 blocks (16 oc each), 256 threads = 64 pooled pos x 4 ocq (4 oc per thread)
__global__ __launch_bounds__(256) void k_conv2(const float* __restrict__ z1p,
    const float* __restrict__ wc, float4* __restrict__ s2v, float4* __restrict__ s2i,
    float* __restrict__ z2p)
{
  const int b = blockIdx.x >> 2;
  const int g = blockIdx.x & 3;
  const int tid = threadIdx.x;
  __shared__ float zs[32][18][18];
  __shared__ float wl[16][288];
  for (int idx = tid; idx < 32 * 18 * 18; idx += 256) {
    int ic = idx / 324, r = idx % 324;
    int hh = r / 18, ww = r % 18;
    float v = 0.0f;
    if (hh >= 1 && hh <= 16 && ww >= 1 && ww <= 16)
      v = z1p[((b * 32 + ic) * 16 + (hh - 1)) * 16 + (ww - 1)];
    zs[ic][hh][ww] = v;
  }
  for (int idx = tid; idx < 16 * 288; idx += 256)
    wl[idx / 288][idx % 288] = wc[g * (16 * 288) + idx];
  __syncthreads();
  const int po = tid & 63, ocq = tid >> 6;
  const int ph = po >> 3, pw = po & 7;
  float acc[4][4] = {{0}};
  for (int ic = 0; ic < 32; ++ic) {
    float p[4][4];
#pragma unroll
    for (int r = 0; r < 4; ++r)
#pragma unroll
      for (int cc = 0; cc < 4; ++cc)
        p[r][cc] = zs[ic][2 * ph + r][2 * pw + cc];
#pragma unroll
    for (int j = 0; j < 4; ++j) {
      const float* w = &wl[ocq * 4 + j][ic * 9];
#pragma unroll
      for (int kh = 0; kh < 3; ++kh)
#pragma unroll
        for (int kw = 0; kw < 3; ++kw) {
          const float wv = w[kh * 3 + kw];
          acc[j][0] = fmaf(p[kh][kw],         wv, acc[j][0]);
          acc[j][1] = fmaf(p[kh][kw + 1],     wv, acc[j][1]);
          acc[j][2] = fmaf(p[kh + 1][kw],     wv, acc[j][2]);
          acc[j][3] = fmaf(p[kh + 1][kw + 1], wv, acc[j][3]);
        }
    }
  }
#pragma unroll
  for (int j = 0; j < 4; ++j) {
    const int oc = g * 16 + ocq * 4 + j;
    const int sidx = ((b * 64 + oc) * 8 + ph) * 8 + pw;
    float4 v4 = s2v[sidx], i4 = s2i[sidx];
    float z0 = lif1(acc[j][0], 0.2f, v4.x, i4.x);
    float z1 = lif1(acc[j][1], 0.2f, v4.y, i4.y);
    float z2 = lif1(acc[j][2], 0.2f, v4.z, i4.z);
    float z3 = lif1(acc[j][3], 0.2f, v4.w, i4.w);
    s2v[sidx] = v4; s2i[sidx] = i4;
    z2p[sidx] = 0.25f * (z0 + z1 + z2 + z3);
  }
}

// ---------------- conv3 (64->128) @8x8 + LIF(0.1) + pool -> z3T[k][b], k = oc*16+ph*4+pw
// grid: B*8 blocks (16 oc each), 256 threads = 16 pooled pos x 16 oc (1 oc per thread)
__global__ __launch_bounds__(256) void k_conv3(const float* __restrict__ z2p,
    const float* __restrict__ wc, float4* __restrict__ s3v, float4* __restrict__ s3i,
    float* __restrict__ z3T)
{
  const int b = blockIdx.x >> 3;
  const int g = blockIdx.x & 7;
  const int tid = threadIdx.x;
  __shared__ float zs[64][10][10];
  __shared__ float wl[16][577];  // pad 576->577: kills 4-way bank conflict (576 % 32 == 0)
  for (int idx = tid; idx < 64 * 100; idx += 256) {
    int ic = idx / 100, r = idx % 100;
    int hh = r / 10, ww = r % 10;
    float v = 0.0f;
    if (hh >= 1 && hh <= 8 && ww >= 1 && ww <= 8)
      v = z2p[((b * 64 + ic) * 8 + (hh - 1)) * 8 + (ww - 1)];
    zs[ic][hh][ww] = v;
  }
  for (int idx = tid; idx < 16 * 576; idx += 256)
    wl[idx / 576][idx % 576] = wc[g * (16 * 576) + idx];
  __syncthreads();
  const int po = tid & 15, ocl = tid >> 4;
  const int ph = po >> 2, pw = po & 3;
  float a0 = 0, a1 = 0, a2 = 0, a3 = 0;
  for (int ic = 0; ic < 64; ++ic) {
    float p[4][4];
#pragma unroll
    for (int r = 0; r < 4; ++r)
#pragma unroll
      for (int cc = 0; cc < 4; ++cc)
        p[r][cc] = zs[ic][2 * ph + r][2 * pw + cc];
    const float* w = &wl[ocl][ic * 9];
#pragma unroll
    for (int kh = 0; kh < 3; ++kh)
#pragma unroll
      for (int kw = 0; kw < 3; ++kw) {
        const float wv = w[kh * 3 + kw];
        a0 = fmaf(p[kh][kw],         wv, a0);
        a1 = fmaf(p[kh][kw + 1],     wv, a1);
        a2 = fmaf(p[kh + 1][kw],     wv, a2);
        a3 = fmaf(p[kh + 1][kw + 1], wv, a3);
      }
  }
  const int oc = g * 16 + ocl;
  const int sidx = ((b * 128 + oc) * 4 + ph) * 4 + pw;
  float4 v4 = s3v[sidx], i4 = s3i[sidx];
  float z0 = lif1(a0, 0.1f, v4.x, i4.x);
  float z1 = lif1(a1, 0.1f, v4.y, i4.y);
  float z2 = lif1(a2, 0.1f, v4.z, i4.z);
  float z3 = lif1(a3, 0.1f, v4.w, i4.w);
  s3v[sidx] = v4; s3i[sidx] = i4;
  z3T[(oc * 16 + po) * 128 + b] = 0.25f * (z0 + z1 + z2 + z3);
}

// ---------------- fc1 partials: split-K=8. grid 1024 blocks.
// thread: lanes = b (coalesced z3T), 4 consecutive n rows, K-chunk 256.
__global__ __launch_bounds__(256) void k_fc1(const float* __restrict__ z3T,
    const float* __restrict__ w1, float* __restrict__ P)
{
  const int bid = blockIdx.x;
  const int ks = bid >> 7;        // 0..7
  const int nb = bid & 127;
  const int tid = threadIdx.x;
  const int b = tid & 127;
  const int ng = tid >> 7;        // 0..1
  const int n0 = (nb * 2 + ng) * 4;
  const int kbase = ks * 256;
  const float* w0 = w1 + (size_t)(n0 + 0) * 2048 + kbase;
  const float* wa = w1 + (size_t)(n0 + 1) * 2048 + kbase;
  const float* wb = w1 + (size_t)(n0 + 2) * 2048 + kbase;
  const float* wd = w1 + (size_t)(n0 + 3) * 2048 + kbase;
  const float* zp = z3T + (size_t)kbase * 128 + b;
  float a0 = 0, a1 = 0, a2 = 0, a3 = 0;
#pragma unroll 4
  for (int k = 0; k < 256; ++k) {
    const float zv = zp[(size_t)k * 128];
    a0 = fmaf(zv, w0[k], a0);
    a1 = fmaf(zv, wa[k], a1);
    a2 = fmaf(zv, wb[k], a2);
    a3 = fmaf(zv, wd[k], a3);
  }
  float* Pp = P + (size_t)ks * 131072 + (size_t)n0 * 128 + b;
  Pp[0] = a0; Pp[128] = a1; Pp[256] = a2; Pp[384] = a3;
}

// ---------------- fc1 reduce + LIF(0.1) -> z4T[n][b]
__global__ __launch_bounds__(256) void k_fc1b(const float* __restrict__ P,
    float* __restrict__ s4v, float* __restrict__ s4i, float* __restrict__ z4T)
{
  const int idx = blockIdx.x * 256 + threadIdx.x;  // < 131072
  float a = 0;
#pragma unroll
  for (int s = 0; s < 8; ++s) a += P[(size_t)s * 131072 + idx];
  float v = s4v[idx], i = s4i[idx];
  float z = lif1(a, 0.1f, v, i);
  s4v[idx] = v; s4i[idx] = i;
  z4T[idx] = z;
}

// ---------------- out layer (1024->10) + LI + running max into d_out
// grid 20 blocks: (o, bgroup). 256 threads = 64 b-lanes x 4 K-quarters.
__global__ __launch_bounds__(256) void k_out(const float* __restrict__ z4T,
    const float* __restrict__ wo, float* __restrict__ sov, float* __restrict__ soi,
    float* __restrict__ out, int t)
{
  const int o = blockIdx.x >> 1;
  const int bg = blockIdx.x & 1;
  const int tid = threadIdx.x;
  const int lane = tid & 63;
  const int kq = tid >> 6;
  const int b = bg * 64 + lane;
  const float* w = wo + o * 1024 + kq * 256;
  const float* zp = z4T + (size_t)(kq * 256) * 128 + b;
  float a = 0;
#pragma unroll 4
  for (int k = 0; k < 256; ++k)
    a = fmaf(zp[(size_t)k * 128], w[k], a);
  __shared__ float red[4][64];
  red[kq][lane] = a;
  __syncthreads();
  if (kq == 0) {
    float s = red[0][lane] + red[1][lane] + red[2][lane] + red[3][lane];
    const int si = o * 128 + b;
    float v = sov[si], i = soi[si];
    float vn = fmaf(0.1f, i - v, v);
    soi[si] = fmaf(0.8f, i, s);
    sov[si] = vn;
    float* op = out + b * 10 + o;
    if (t == 0) *op = vn;
    else *op = fmaxf(*op, vn);
  }
}

extern "C" void kernel_launch(void* const* d_in, const int* in_sizes, int n_in,
                              void* d_out, int out_size, void* d_ws, size_t ws_size,
                              hipStream_t stream)
{
  const float* x   = (const float*)d_in[0];   // (16,128,3,32,32)
  const float* wc1 = (const float*)d_in[1];   // (32,3,3,3)
  const float* wc2 = (const float*)d_in[2];   // (64,32,3,3)
  const float* wc3 = (const float*)d_in[3];   // (128,64,3,3)
  const float* wf1 = (const float*)d_in[4];   // (1024,2048)
  const float* wo  = (const float*)d_in[5];   // (10,1024)
  float* out = (float*)d_out;                 // (128,10)
  float* ws = (float*)d_ws;

  // workspace layout (float offsets)
  float4* s1v = (float4*)(ws + 0);            // B*32*16*16 float4
  float4* s1i = (float4*)(ws + 4194304);
  float4* s2v = (float4*)(ws + 8388608);      // B*64*4*4*... (B,64,8,8) float4
  float4* s2i = (float4*)(ws + 10485760);
  float4* s3v = (float4*)(ws + 12582912);     // (B,128,4,4) float4
  float4* s3i = (float4*)(ws + 13631488);
  float* s4v = ws + 14680064;                 // (1024,128)
  float* s4i = ws + 14811136;
  float* sov = ws + 14942208;                 // (10,128)
  float* soi = ws + 14943488;
  float* z1p = ws + 14944768;                 // (B,32,16,16)
  float* z2p = ws + 15993344;                 // (B,64,8,8)
  float* z3T = ws + 16517632;                 // (2048,128)
  float* z4T = ws + 16779776;                 // (1024,128)
  float* P   = ws + 16910848;                 // (8,1024,128)

  // zero all persistent state once per launch (capture-safe)
  hipMemsetAsync(d_ws, 0, 14944768ull * 4ull, stream);

  for (int t = 0; t < 16; ++t) {
    const float* xt = x + (size_t)t * 393216;  // B*3*32*32
    k_conv1<<<256, 256, 0, stream>>>(xt, wc1, s1v, s1i, z1p);
    k_conv2<<<512, 256, 0, stream>>>(z1p, wc2, s2v, s2i, z2p);
    k_conv3<<<1024, 256, 0, stream>>>(z2p, wc3, s3v, s3i, z3T);
    k_fc1 <<<1024, 256, 0, stream>>>(z3T, wf1, P);
    k_fc1b<<<512, 256, 0, stream>>>(P, s4v, s4i, z4T);
    k_out <<<20, 256, 0, stream>>>(z4T, wo, sov, soi, out, t);
  }
}

// Round 2
// 3008.707 us; speedup vs baseline: 1.0399x; 1.0399x over previous
//
#include <hip/hip_runtime.h>

// ConvSNN forward: T=16, B=128. All fp32.
// LIF: v_dec = v + 0.1*(i - v); z = (v_dec > vth); v' = z?0:v_dec; i' = 0.8*i + inp
// LI : v' = v + 0.1*(i - v); i' = 0.8*i + inp

__device__ __forceinline__ float lif1(float inp, float vth, float& v, float& i) {
  float vd = fmaf(0.1f, i - v, v);
  float z = (vd > vth) ? 1.0f : 0.0f;
  v = (vd > vth) ? 0.0f : vd;
  i = fmaf(0.8f, i, inp);
  return z;
}

// ---------------- one-time weight transposes ----------------
__global__ __launch_bounds__(256) void k_tr2(const float* __restrict__ wc2, float* __restrict__ wT2) {
  int idx = blockIdx.x * 256 + threadIdx.x;           // 288*64
  if (idx < 288 * 64) { int k = idx >> 6, oc = idx & 63; wT2[idx] = wc2[oc * 288 + k]; }
}
__global__ __launch_bounds__(256) void k_tr3(const float* __restrict__ wc3, float* __restrict__ wT3) {
  int idx = blockIdx.x * 256 + threadIdx.x;           // 576*128
  if (idx < 576 * 128) { int k = idx >> 7, oc = idx & 127; wT3[idx] = wc3[oc * 576 + k]; }
}

// ---------------- conv1 (3->32) @32x32 + LIF(0.25) + pool -> z1p (B,32,16,16)
__global__ __launch_bounds__(256) void k_conv1(const float* __restrict__ x,
    const float* __restrict__ wc, float4* __restrict__ s1v, float4* __restrict__ s1i,
    float* __restrict__ z1p)
{
  const int b = blockIdx.x >> 1;
  const int g = blockIdx.x & 1;
  const int tid = threadIdx.x;
  __shared__ float xs[3][34][34];
  __shared__ float wl[16 * 27];
  for (int idx = tid; idx < 16 * 27; idx += 256) wl[idx] = wc[g * (16 * 27) + idx];
  for (int idx = tid; idx < 3 * 34 * 34; idx += 256) {
    int c = idx / 1156, r = idx % 1156;
    int hh = r / 34, ww = r % 34;
    float v = 0.0f;
    if (hh >= 1 && hh <= 32 && ww >= 1 && ww <= 32)
      v = x[((b * 3 + c) * 32 + (hh - 1)) * 32 + (ww - 1)];
    xs[c][hh][ww] = v;
  }
  __syncthreads();
  const int ph = tid >> 4, pw = tid & 15;
  float p[3][4][4];
#pragma unroll
  for (int c = 0; c < 3; ++c)
#pragma unroll
    for (int r = 0; r < 4; ++r)
#pragma unroll
      for (int cc = 0; cc < 4; ++cc)
        p[c][r][cc] = xs[c][2 * ph + r][2 * pw + cc];

  for (int j = 0; j < 16; ++j) {
    float s00 = 0, s01 = 0, s10 = 0, s11 = 0;
    const float* w = &wl[j * 27];
#pragma unroll
    for (int c = 0; c < 3; ++c)
#pragma unroll
      for (int kh = 0; kh < 3; ++kh)
#pragma unroll
        for (int kw = 0; kw < 3; ++kw) {
          const float wv = w[(c * 3 + kh) * 3 + kw];
          s00 = fmaf(p[c][kh][kw],         wv, s00);
          s01 = fmaf(p[c][kh][kw + 1],     wv, s01);
          s10 = fmaf(p[c][kh + 1][kw],     wv, s10);
          s11 = fmaf(p[c][kh + 1][kw + 1], wv, s11);
        }
    const int oc = g * 16 + j;
    const int sidx = ((b * 32 + oc) * 16 + ph) * 16 + pw;
    float4 v4 = s1v[sidx], i4 = s1i[sidx];
    float z0 = lif1(s00, 0.25f, v4.x, i4.x);
    float z1 = lif1(s01, 0.25f, v4.y, i4.y);
    float z2 = lif1(s10, 0.25f, v4.z, i4.z);
    float z3 = lif1(s11, 0.25f, v4.w, i4.w);
    s1v[sidx] = v4; s1i[sidx] = i4;
    z1p[sidx] = 0.25f * (z0 + z1 + z2 + z3);
  }
}

// ---------------- conv2 (32->64) @16x16 + LIF(0.2) + pool -> z2p (B,64,8,8)
// grid 256 = B x 2 half-images. 128 thr = 8 ocq (8 oc) x 16 pixg (2x4 px).
__global__ __launch_bounds__(128) void k_conv2(const float* __restrict__ z1p,
    const float* __restrict__ wT2, float4* __restrict__ s2v, float4* __restrict__ s2i,
    float* __restrict__ z2p)
{
  const int b = blockIdx.x >> 1;
  const int ybase = (blockIdx.x & 1) * 8;
  const int tid = threadIdx.x;
  __shared__ float zs[32][10][20];   // rows ybase-1..ybase+8, cols: 0 pad,1..16,17 pad,18-19 zero
  __shared__ float wl[72][68];
  for (int idx = tid; idx < 32 * 200; idx += 128) {
    int ic = idx / 200, r = idx % 200;
    int row = r / 20, col = r % 20;
    int gy = ybase + row - 1, gx = col - 1;
    float v = 0.0f;
    if (gy >= 0 && gy < 16 && gx >= 0 && gx < 16)
      v = z1p[((b * 32 + ic) * 16 + gy) * 16 + gx];
    zs[ic][row][col] = v;
  }
  const int pixg = tid & 15, ocq = tid >> 4;
  const int y0 = ((pixg >> 2) & 3) * 2;   // 0,2,4,6 (local out row)
  const int x0 = (pixg & 3) * 4;          // 0,4,8,12
  const int oc0 = ocq * 8;
  float acc[8][2][4] = {};
  for (int c = 0; c < 4; ++c) {            // 8-ic chunks
    __syncthreads();
    for (int idx = tid; idx < 72 * 64; idx += 128) {
      int kl = idx >> 6, oc = idx & 63;
      wl[kl][oc] = wT2[(c * 72 + kl) * 64 + oc];
    }
    __syncthreads();
    for (int icl = 0; icl < 8; ++icl) {
      const int ic = c * 8 + icl;
#pragma unroll
      for (int dy = 0; dy < 3; ++dy) {
        const float4 a0 = *(const float4*)&zs[ic][y0 + dy][x0];
        const float4 a1 = *(const float4*)&zs[ic][y0 + dy][x0 + 4];
        const float4 c0 = *(const float4*)&zs[ic][y0 + 1 + dy][x0];
        const float4 c1 = *(const float4*)&zs[ic][y0 + 1 + dy][x0 + 4];
        const float ra[8] = {a0.x, a0.y, a0.z, a0.w, a1.x, a1.y, a1.z, a1.w};
        const float rb[8] = {c0.x, c0.y, c0.z, c0.w, c1.x, c1.y, c1.z, c1.w};
#pragma unroll
        for (int dx = 0; dx < 3; ++dx) {
          const int kl = icl * 9 + dy * 3 + dx;
          const float4 w0 = *(const float4*)&wl[kl][oc0];
          const float4 w1 = *(const float4*)&wl[kl][oc0 + 4];
          const float wv[8] = {w0.x, w0.y, w0.z, w0.w, w1.x, w1.y, w1.z, w1.w};
#pragma unroll
          for (int j = 0; j < 8; ++j) {
#pragma unroll
            for (int cc = 0; cc < 4; ++cc) {
              acc[j][0][cc] = fmaf(ra[dx + cc], wv[j], acc[j][0][cc]);
              acc[j][1][cc] = fmaf(rb[dx + cc], wv[j], acc[j][1][cc]);
            }
          }
        }
      }
    }
  }
  const int ph = (ybase + y0) >> 1;
#pragma unroll
  for (int j = 0; j < 8; ++j) {
    const int oc = oc0 + j;
#pragma unroll
    for (int pp = 0; pp < 2; ++pp) {
      const int pw = (x0 >> 1) + pp;
      const int sidx = ((b * 64 + oc) * 8 + ph) * 8 + pw;
      float4 v4 = s2v[sidx], i4 = s2i[sidx];
      float z0 = lif1(acc[j][0][2 * pp],     0.2f, v4.x, i4.x);
      float z1 = lif1(acc[j][0][2 * pp + 1], 0.2f, v4.y, i4.y);
      float z2 = lif1(acc[j][1][2 * pp],     0.2f, v4.z, i4.z);
      float z3 = lif1(acc[j][1][2 * pp + 1], 0.2f, v4.w, i4.w);
      s2v[sidx] = v4; s2i[sidx] = i4;
      z2p[sidx] = 0.25f * (z0 + z1 + z2 + z3);
    }
  }
}

// ---------------- conv3 (64->128) @8x8, K-split 2 -> P3[2][B][128][8][8] (pre-LIF partials)
// grid 256 = ks(2) x bg(64: 2 b) x ocg(2: 64 oc). 128 thr = 8 ocq x 16 pixg (2b x 8 quads).
__global__ __launch_bounds__(128) void k_conv3(const float* __restrict__ z2p,
    const float* __restrict__ wT3, float* __restrict__ P3)
{
  const int ocg = blockIdx.x & 1;
  const int bg  = (blockIdx.x >> 1) & 63;
  const int ks  = blockIdx.x >> 7;
  const int b0 = bg * 2, icbase = ks * 32;
  const int tid = threadIdx.x;
  __shared__ float zs[2][32][10][12];
  __shared__ float wl[72][68];
  for (int idx = tid; idx < 2 * 32 * 120; idx += 128) {
    int bl = idx / 3840, r = idx % 3840;
    int ic = r / 120, rr = r % 120;
    int row = rr / 12, col = rr % 12;
    int gy = row - 1, gx = col - 1;
    float v = 0.0f;
    if (gy >= 0 && gy < 8 && gx >= 0 && gx < 8)
      v = z2p[(((b0 + bl) * 64 + icbase + ic) * 8 + gy) * 8 + gx];
    zs[bl][ic][row][col] = v;
  }
  const int pixg = tid & 15, ocq = tid >> 4;
  const int bl = pixg >> 3;
  const int y0 = ((pixg >> 1) & 3) * 2;   // 0,2,4,6
  const int x0 = (pixg & 1) * 4;          // 0,4
  float acc[8][2][4] = {};
  for (int c = 0; c < 4; ++c) {            // 8-ic chunks within this split
    __syncthreads();
    for (int idx = tid; idx < 72 * 64; idx += 128) {
      int kl = idx >> 6, oc = idx & 63;
      wl[kl][oc] = wT3[((icbase + c * 8) * 9 + kl) * 128 + ocg * 64 + oc];
    }
    __syncthreads();
    for (int icl = 0; icl < 8; ++icl) {
      const int ic = c * 8 + icl;
#pragma unroll
      for (int dy = 0; dy < 3; ++dy) {
        const float4 a0 = *(const float4*)&zs[bl][ic][y0 + dy][x0];
        const float4 a1 = *(const float4*)&zs[bl][ic][y0 + dy][x0 + 4];
        const float4 c0 = *(const float4*)&zs[bl][ic][y0 + 1 + dy][x0];
        const float4 c1 = *(const float4*)&zs[bl][ic][y0 + 1 + dy][x0 + 4];
        const float ra[8] = {a0.x, a0.y, a0.z, a0.w, a1.x, a1.y, a1.z, a1.w};
        const float rb[8] = {c0.x, c0.y, c0.z, c0.w, c1.x, c1.y, c1.z, c1.w};
#pragma unroll
        for (int dx = 0; dx < 3; ++dx) {
          const int kl = icl * 9 + dy * 3 + dx;
          const float4 w0 = *(const float4*)&wl[kl][ocq * 8];
          const float4 w1 = *(const float4*)&wl[kl][ocq * 8 + 4];
          const float wv[8] = {w0.x, w0.y, w0.z, w0.w, w1.x, w1.y, w1.z, w1.w};
#pragma unroll
          for (int j = 0; j < 8; ++j) {
#pragma unroll
            for (int cc = 0; cc < 4; ++cc) {
              acc[j][0][cc] = fmaf(ra[dx + cc], wv[j], acc[j][0][cc]);
              acc[j][1][cc] = fmaf(rb[dx + cc], wv[j], acc[j][1][cc]);
            }
          }
        }
      }
    }
  }
  const int b = b0 + bl;
#pragma unroll
  for (int j = 0; j < 8; ++j) {
    const int oc = ocg * 64 + ocq * 8 + j;
    float* base = P3 + (size_t)ks * 1048576 + ((size_t)b * 128 + oc) * 64;
#pragma unroll
    for (int r = 0; r < 2; ++r)
      *(float4*)&base[(y0 + r) * 8 + x0] = *(float4*)&acc[j][r][0];
  }
}

// ---------------- conv3 reduce + LIF(0.1) + pool -> z3T[k][b]
__global__ __launch_bounds__(256) void k_c3red(const float* __restrict__ P3,
    float4* __restrict__ s3v, float4* __restrict__ s3i, float* __restrict__ z3T)
{
  const int idx = blockIdx.x * 256 + threadIdx.x;   // 262144 = ((b*128+oc)*4+ph)*4+pw
  const int pw = idx & 3, ph = (idx >> 2) & 3, oc = (idx >> 4) & 127, b = idx >> 11;
  const float* p0 = P3 + ((size_t)b * 128 + oc) * 64;
  const float* p1 = p0 + 1048576;
  const int r0 = (2 * ph) * 8 + 2 * pw, r1 = r0 + 8;
  float a00 = p0[r0]     + p1[r0];
  float a01 = p0[r0 + 1] + p1[r0 + 1];
  float a10 = p0[r1]     + p1[r1];
  float a11 = p0[r1 + 1] + p1[r1 + 1];
  float4 v4 = s3v[idx], i4 = s3i[idx];
  float z0 = lif1(a00, 0.1f, v4.x, i4.x);
  float z1 = lif1(a01, 0.1f, v4.y, i4.y);
  float z2 = lif1(a10, 0.1f, v4.z, i4.z);
  float z3 = lif1(a11, 0.1f, v4.w, i4.w);
  s3v[idx] = v4; s3i[idx] = i4;
  z3T[(oc * 16 + ph * 4 + pw) * 128 + b] = 0.25f * (z0 + z1 + z2 + z3);
}

// ---------------- fc1 partials: K-split 16. grid 256 = nb(16: 64 n) x ks(16: 128 k).
// 128 thr = 8 nq (8 n) x 16 bq (8 b). Two 64-k staged sub-chunks.
__global__ __launch_bounds__(128) void k_fc1(const float* __restrict__ z3T,
    const float* __restrict__ w1, float* __restrict__ P1)
{
  const int nb = blockIdx.x >> 4, ks = blockIdx.x & 15;
  const int nbase = nb * 64, kbase0 = ks * 128;
  const int tid = threadIdx.x;
  __shared__ float zl[64][128];
  __shared__ float wl[64][69];
  const int bq = tid & 15, nq = tid >> 4;
  const int b0 = bq * 8, n0 = nq * 8;
  float acc[8][8] = {};
  for (int sc = 0; sc < 2; ++sc) {
    const int kbase = kbase0 + sc * 64;
    __syncthreads();
    for (int idx = tid; idx < 2048; idx += 128) {           // z slab: 64k x 128b
      int k = idx >> 5, c4 = (idx & 31) * 4;
      *(float4*)&zl[k][c4] = *(const float4*)&z3T[(kbase + k) * 128 + c4];
    }
    for (int idx = tid; idx < 1024; idx += 128) {           // w slab: 64n x 64k
      int n = idx >> 4, c4 = (idx & 15) * 4;
      float4 t = *(const float4*)&w1[(size_t)(nbase + n) * 2048 + kbase + c4];
      wl[n][c4] = t.x; wl[n][c4 + 1] = t.y; wl[n][c4 + 2] = t.z; wl[n][c4 + 3] = t.w;
    }
    __syncthreads();
    for (int k = 0; k < 64; ++k) {
      const float4 z0 = *(const float4*)&zl[k][b0];
      const float4 z1 = *(const float4*)&zl[k][b0 + 4];
      const float zz[8] = {z0.x, z0.y, z0.z, z0.w, z1.x, z1.y, z1.z, z1.w};
#pragma unroll
      for (int j = 0; j < 8; ++j) {
        const float wv = wl[n0 + j][k];
#pragma unroll
        for (int cc = 0; cc < 8; ++cc)
          acc[j][cc] = fmaf(zz[cc], wv, acc[j][cc]);
      }
    }
  }
#pragma unroll
  for (int j = 0; j < 8; ++j) {
    float* p = P1 + (size_t)ks * 131072 + (size_t)(nbase + n0 + j) * 128 + b0;
    *(float4*)&p[0] = *(float4*)&acc[j][0];
    *(float4*)&p[4] = *(float4*)&acc[j][4];
  }
}

// ---------------- fc1 reduce + LIF(0.1) -> z4T[n][b]
__global__ __launch_bounds__(256) void k_fc1b(const float* __restrict__ P,
    float* __restrict__ s4v, float* __restrict__ s4i, float* __restrict__ z4T)
{
  const int idx = blockIdx.x * 256 + threadIdx.x;  // < 131072
  float a = 0;
#pragma unroll
  for (int s = 0; s < 16; ++s) a += P[(size_t)s * 131072 + idx];
  float v = s4v[idx], i = s4i[idx];
  float z = lif1(a, 0.1f, v, i);
  s4v[idx] = v; s4i[idx] = i;
  z4T[idx] = z;
}

// ---------------- out layer (1024->10) + LI + running max into d_out
__global__ __launch_bounds__(256) void k_out(const float* __restrict__ z4T,
    const float* __restrict__ wo, float* __restrict__ sov, float* __restrict__ soi,
    float* __restrict__ out, int t)
{
  const int o = blockIdx.x >> 1;
  const int bg = blockIdx.x & 1;
  const int tid = threadIdx.x;
  const int lane = tid & 63;
  const int kq = tid >> 6;
  const int b = bg * 64 + lane;
  const float* w = wo + o * 1024 + kq * 256;
  const float* zp = z4T + (size_t)(kq * 256) * 128 + b;
  float a = 0;
#pragma unroll 4
  for (int k = 0; k < 256; ++k)
    a = fmaf(zp[(size_t)k * 128], w[k], a);
  __shared__ float red[4][64];
  red[kq][lane] = a;
  __syncthreads();
  if (kq == 0) {
    float s = red[0][lane] + red[1][lane] + red[2][lane] + red[3][lane];
    const int si = o * 128 + b;
    float v = sov[si], i = soi[si];
    float vn = fmaf(0.1f, i - v, v);
    soi[si] = fmaf(0.8f, i, s);
    sov[si] = vn;
    float* op = out + b * 10 + o;
    if (t == 0) *op = vn;
    else *op = fmaxf(*op, vn);
  }
}

extern "C" void kernel_launch(void* const* d_in, const int* in_sizes, int n_in,
                              void* d_out, int out_size, void* d_ws, size_t ws_size,
                              hipStream_t stream)
{
  const float* x   = (const float*)d_in[0];   // (16,128,3,32,32)
  const float* wc1 = (const float*)d_in[1];   // (32,3,3,3)
  const float* wc2 = (const float*)d_in[2];   // (64,32,3,3)
  const float* wc3 = (const float*)d_in[3];   // (128,64,3,3)
  const float* wf1 = (const float*)d_in[4];   // (1024,2048)
  const float* wo  = (const float*)d_in[5];   // (10,1024)
  float* out = (float*)d_out;                 // (128,10)
  float* ws = (float*)d_ws;

  // workspace layout (float offsets)
  float4* s1v = (float4*)(ws + 0);            // (B,32,16,16) float4 sites
  float4* s1i = (float4*)(ws + 4194304);
  float4* s2v = (float4*)(ws + 8388608);      // (B,64,8,8) float4 sites
  float4* s2i = (float4*)(ws + 10485760);
  float4* s3v = (float4*)(ws + 12582912);     // (B,128,4,4) float4 sites
  float4* s3i = (float4*)(ws + 13631488);
  float* s4v = ws + 14680064;                 // (1024,128)
  float* s4i = ws + 14811136;
  float* sov = ws + 14942208;                 // (10,128)
  float* soi = ws + 14943488;
  float* z1p = ws + 14944768;                 // (B,32,16,16)
  float* z2p = ws + 15993344;                 // (B,64,8,8)
  float* z3T = ws + 16517632;                 // (2048,128)
  float* z4T = ws + 16779776;                 // (1024,128)
  float* P   = ws + 16910848;                 // 2,097,152 floats: P3[2][...] / P1[16][...]
  float* wT2 = ws + 19008000;                 // (288,64)
  float* wT3 = ws + 19026432;                 // (576,128)
  // end: 19,100,160 floats = 76.4 MB

  // one-time weight transposes + state zeroing (capture-safe)
  k_tr2<<<72, 256, 0, stream>>>(wc2, wT2);
  k_tr3<<<288, 256, 0, stream>>>(wc3, wT3);
  hipMemsetAsync(d_ws, 0, 14944768ull * 4ull, stream);

  for (int t = 0; t < 16; ++t) {
    const float* xt = x + (size_t)t * 393216;  // B*3*32*32
    k_conv1<<<256, 256, 0, stream>>>(xt, wc1, s1v, s1i, z1p);
    k_conv2<<<256, 128, 0, stream>>>(z1p, wT2, s2v, s2i, z2p);
    k_conv3<<<256, 128, 0, stream>>>(z2p, wT3, P);
    k_c3red<<<1024, 256, 0, stream>>>(P, s3v, s3i, z3T);
    k_fc1 <<<256, 128, 0, stream>>>(z3T, wf1, P);
    k_fc1b<<<512, 256, 0, stream>>>(P, s4v, s4i, z4T);
    k_out <<<20, 256, 0, stream>>>(z4T, wo, sov, soi, out, t);
  }
}

// Round 5
// 1073.459 us; speedup vs baseline: 2.9147x; 2.8028x over previous
//
#include <hip/hip_runtime.h>

// ConvSNN forward, T=16, B=128. conv2/conv3/fc1 via MFMA bf16 with TRIPLE-split
// weights (hi+mid+lo bf16 ~= fp32 to ~2^-27 rel); activations are pooled spikes
// in {0,.25,.5,.75,1}, exact in bf16. LIF/LI state kept in fp32.
// LIF: vd = v + 0.1*(i - v); z = (vd>th); v' = z?0:vd; i' = 0.8*i + inp

typedef __attribute__((ext_vector_type(8))) short bf16x8;
typedef __attribute__((ext_vector_type(4))) float f32x4;

__device__ __forceinline__ unsigned short f2bf(float f) {
  unsigned int u = __float_as_uint(f);
  return (unsigned short)((u + 0x7fffu + ((u >> 16) & 1u)) >> 16);
}
__device__ __forceinline__ float bf2f(unsigned short h) {
  return __uint_as_float(((unsigned int)h) << 16);
}
__device__ __forceinline__ unsigned short split3(float wv, int sp) {
  unsigned short hi = f2bf(wv);
  float r1 = wv - bf2f(hi);
  unsigned short mid = f2bf(r1);
  if (sp == 0) return hi;
  if (sp == 1) return mid;
  return f2bf(r1 - bf2f(mid));
}
__device__ __forceinline__ float lif1(float inp, float vth, float& v, float& i) {
  float vd = fmaf(0.1f, i - v, v);
  float z = (vd > vth) ? 1.0f : 0.0f;
  v = (vd > vth) ? 0.0f : vd;
  i = fmaf(0.8f, i, inp);
  return z;
}
__device__ __forceinline__ f32x4 mfma16(bf16x8 a, bf16x8 b, f32x4 c) {
  return __builtin_amdgcn_mfma_f32_16x16x32_bf16(a, b, c, 0, 0, 0);
}

// ---------- one-time weight split+pack into B-fragment order ----------
// layout: [ocg 2][sp 3][dydx 9][g 4][ocl 32][j 8]  (ic = 8g+j); 55296 entries
__global__ __launch_bounds__(256) void k_pack2(const float* __restrict__ wc2,
                                               unsigned short* __restrict__ wpk) {
  int idx = blockIdx.x * 256 + threadIdx.x;
  if (idx >= 55296) return;
  int j = idx & 7, ocl = (idx >> 3) & 31, g = (idx >> 8) & 3;
  int r = idx >> 10;                        // 0..53
  int dydx = r % 9; int q = r / 9;          // 0..5
  int sp = q % 3, ocg = q / 3;
  int oc = ocg * 32 + ocl, ic = g * 8 + j;
  wpk[idx] = split3(wc2[(oc * 32 + ic) * 9 + dydx], sp);
}
// layout: [ics 2][ocg 4][sp 3][dydx 9][g 4][ocl 32][j 8]  (ic = ics*32+8g+j); 442368
__global__ __launch_bounds__(256) void k_pack3(const float* __restrict__ wc3,
                                               unsigned short* __restrict__ wpk) {
  int idx = blockIdx.x * 256 + threadIdx.x;
  if (idx >= 442368) return;
  int j = idx & 7, ocl = (idx >> 3) & 31, g = (idx >> 8) & 3;
  int r = idx >> 10;                        // 0..431
  int dydx = r % 9; int q = r / 9;          // 0..47
  int sp = q % 3, ocg = (q / 3) & 3, ics = q / 12;
  int oc = ocg * 32 + ocl, ic = ics * 32 + g * 8 + j;
  wpk[idx] = split3(wc3[(oc * 64 + ic) * 9 + dydx], sp);
}

// ---------- conv1 (3->32) fp32 + LIF(0.25) + pool -> z1bf (B,16,16,32) bf16 ----------
// grid 512 = b(128) x h(2 halves) x g(2 oc-groups); 256 thr = 128 pooled sites x 2 sub
__global__ __launch_bounds__(256) void k_conv1(const float* __restrict__ x,
    const float* __restrict__ wc, float4* __restrict__ s1v, float4* __restrict__ s1i,
    unsigned short* __restrict__ z1bf)
{
  const int bid = blockIdx.x;
  const int g = bid & 1, h = (bid >> 1) & 1, b = bid >> 2;
  const int tid = threadIdx.x;
  __shared__ float xs[3][18][34];
  __shared__ float wl[16][27];
  for (int i = tid; i < 432; i += 256) wl[i / 27][i % 27] = wc[g * 432 + i];
  for (int i = tid; i < 3 * 18 * 34; i += 256) {
    int c = i / 612, rr = i % 612;
    int row = rr / 34, col = rr % 34;
    int gy = h * 16 + row - 1, gx = col - 1;
    float v = 0.f;
    if (gy >= 0 && gy < 32 && gx >= 0 && gx < 32)
      v = x[((b * 3 + c) * 32 + gy) * 32 + gx];
    xs[c][row][col] = v;
  }
  __syncthreads();
  const int site = tid >> 1, sub = tid & 1;
  const int ph = site >> 4, pw = site & 15;
  float p[3][4][4];
#pragma unroll
  for (int c = 0; c < 3; ++c)
#pragma unroll
    for (int r = 0; r < 4; ++r)
#pragma unroll
      for (int cc = 0; cc < 4; ++cc)
        p[c][r][cc] = xs[c][2 * ph + r][2 * pw + cc];
  unsigned short zout[8];
  const int py = h * 8 + ph;
#pragma unroll
  for (int jj = 0; jj < 8; ++jj) {
    const float* wv = &wl[sub * 8 + jj][0];
    float s00 = 0, s01 = 0, s10 = 0, s11 = 0;
#pragma unroll
    for (int c = 0; c < 3; ++c)
#pragma unroll
      for (int kh = 0; kh < 3; ++kh)
#pragma unroll
        for (int kw = 0; kw < 3; ++kw) {
          float wvv = wv[(c * 3 + kh) * 3 + kw];
          s00 = fmaf(p[c][kh][kw],     wvv, s00);
          s01 = fmaf(p[c][kh][kw+1],   wvv, s01);
          s10 = fmaf(p[c][kh+1][kw],   wvv, s10);
          s11 = fmaf(p[c][kh+1][kw+1], wvv, s11);
        }
    int oc = g * 16 + sub * 8 + jj;
    int sidx = ((b * 32 + oc) * 16 + py) * 16 + pw;
    float4 v4 = s1v[sidx], i4 = s1i[sidx];
    float z0 = lif1(s00, 0.25f, v4.x, i4.x);
    float z1 = lif1(s01, 0.25f, v4.y, i4.y);
    float z2 = lif1(s10, 0.25f, v4.z, i4.z);
    float z3 = lif1(s11, 0.25f, v4.w, i4.w);
    s1v[sidx] = v4; s1i[sidx] = i4;
    zout[jj] = f2bf(0.25f * (z0 + z1 + z2 + z3));
  }
  *(uint4*)&z1bf[((b * 16 + py) * 16 + pw) * 32 + g * 16 + sub * 8] = *(uint4*)zout;
}

// ---------- conv2 (32->64) MFMA + LIF(0.2) + pool -> z2bf (B,8,8,64) bf16 ----------
// grid 512 = ocg(2) x q(4 row-quads) x bg(64: 2 imgs); 512 thr = 8 waves (2 img x 4 rows)
__global__ __launch_bounds__(512) void k_conv2(const unsigned short* __restrict__ z1bf,
    const unsigned short* __restrict__ wpk, float* __restrict__ s2v, float* __restrict__ s2i,
    unsigned short* __restrict__ z2bf)
{
  const int bid = blockIdx.x;
  const int ocg = bid & 1, q = (bid >> 1) & 3, bg = bid >> 3;
  const int b0 = bg * 2;
  const int tid = threadIdx.x;
  __shared__ __align__(16) unsigned short wl[9216];           // one split: [dydx][g][ocl32][8]
  __shared__ __align__(16) unsigned short img[2][6][18][40];  // ic padded 32->40
  __shared__ __align__(16) unsigned short zpl[8][16][32];
  if (tid < 216) {
    int bl = tid / 108, rr = tid % 108;
    int row = rr / 18, col = rr % 18;
    int gy = q * 4 - 1 + row, gx = col - 1;
    uint4* d = (uint4*)&img[bl][row][col][0];
    uint4 zz = {0, 0, 0, 0};
    if (gy >= 0 && gy < 16 && gx >= 0 && gx < 16) {
      const uint4* s = (const uint4*)(z1bf + (((b0 + bl) * 16 + gy) * 16 + gx) * 32);
      d[0] = s[0]; d[1] = s[1]; d[2] = s[2]; d[3] = s[3]; d[4] = zz;
    } else { d[0] = zz; d[1] = zz; d[2] = zz; d[3] = zz; d[4] = zz; }
  }
  const int w = tid >> 6, l = tid & 63;
  const int bl = w >> 2, wlr = w & 3;
  const int lg = l >> 4, ll = l & 15;
  const uint4* wsrc = (const uint4*)(wpk + ocg * 3 * 9216);
  f32x4 acc[2] = {};
  for (int sp = 0; sp < 3; ++sp) {
    if (sp) __syncthreads();                    // prior MFMA reads done
    for (int i = tid; i < 1152; i += 512) ((uint4*)wl)[i] = wsrc[sp * 1152 + i];
    __syncthreads();
    for (int s9 = 0; s9 < 9; ++s9) {
      const int dy = s9 / 3, dx = s9 % 3;
      bf16x8 a = *(const bf16x8*)&img[bl][wlr + dy][ll + dx][8 * lg];
#pragma unroll
      for (int tl = 0; tl < 2; ++tl) {
        bf16x8 bw = *(const bf16x8*)&wl[(s9 * 4 + lg) * 256 + (tl * 16 + ll) * 8];
        acc[tl] = mfma16(a, bw, acc[tl]);
      }
    }
  }
  const int y = q * 4 + wlr;
  const int b = b0 + bl;
#pragma unroll
  for (int tl = 0; tl < 2; ++tl) {
#pragma unroll
    for (int r = 0; r < 4; ++r) {
      int xx = 4 * lg + r;
      int ocl = tl * 16 + ll;
      int idx = ((b * 16 + y) * 16 + xx) * 64 + ocg * 32 + ocl;
      float v = s2v[idx], ii = s2i[idx];
      float z = lif1(acc[tl][r], 0.2f, v, ii);
      s2v[idx] = v; s2i[idx] = ii;
      zpl[w][xx][ocl] = f2bf(z);
    }
  }
  __syncthreads();
  {
    int e = tid;
    int bl2 = e >> 8, m = (e >> 7) & 1, pp = (e >> 4) & 7, oc2 = (e & 15) * 2;
    int w0 = bl2 * 4 + 2 * m;
    float s0 = bf2f(zpl[w0][2*pp][oc2])   + bf2f(zpl[w0][2*pp+1][oc2]) +
               bf2f(zpl[w0+1][2*pp][oc2]) + bf2f(zpl[w0+1][2*pp+1][oc2]);
    float s1 = bf2f(zpl[w0][2*pp][oc2+1])   + bf2f(zpl[w0][2*pp+1][oc2+1]) +
               bf2f(zpl[w0+1][2*pp][oc2+1]) + bf2f(zpl[w0+1][2*pp+1][oc2+1]);
    unsigned int pk = (unsigned int)f2bf(0.25f * s0) | ((unsigned int)f2bf(0.25f * s1) << 16);
    *(unsigned int*)&z2bf[((((b0 + bl2) * 8) + q * 2 + m) * 8 + pp) * 64 + ocg * 32 + oc2] = pk;
  }
}

// ---------- conv3 (64->128) MFMA, ic-split partials -> P3[2][B][8][8][128] ----------
// grid 512 = ocg(4) x ics(2) x bg(64: 2 imgs); 512 thr = 8 waves (2 img x 4 row-pairs)
__global__ __launch_bounds__(512) void k_conv3(const unsigned short* __restrict__ z2bf,
    const unsigned short* __restrict__ wpk, float* __restrict__ P3)
{
  const int bid = blockIdx.x;
  const int ocg = bid & 3, ics = (bid >> 2) & 1, bg = bid >> 3;
  const int b0 = bg * 2;
  const int tid = threadIdx.x;
  __shared__ __align__(16) unsigned short wl[9216];
  __shared__ __align__(16) unsigned short img[2][10][12][40];
  if (tid < 240) {
    int bl = tid / 120, rr = tid % 120;
    int row = rr / 12, col = rr % 12;
    int gy = row - 1, gx = col - 1;
    uint4* d = (uint4*)&img[bl][row][col][0];
    uint4 zz = {0, 0, 0, 0};
    if (gy >= 0 && gy < 8 && gx >= 0 && gx < 8) {
      const uint4* s = (const uint4*)(z2bf + (((b0 + bl) * 8 + gy) * 8 + gx) * 64 + ics * 32);
      d[0] = s[0]; d[1] = s[1]; d[2] = s[2]; d[3] = s[3]; d[4] = zz;
    } else { d[0] = zz; d[1] = zz; d[2] = zz; d[3] = zz; d[4] = zz; }
  }
  const int w = tid >> 6, l = tid & 63;
  const int bl = w >> 2, q3 = w & 3;
  const int lg = l >> 4, ll = l & 15;
  const int ry = ll >> 3, xi = ll & 7;
  const uint4* wsrc = (const uint4*)(wpk + (ics * 4 + ocg) * 3 * 9216);
  f32x4 acc[2] = {};
  for (int sp = 0; sp < 3; ++sp) {
    if (sp) __syncthreads();
    for (int i = tid; i < 1152; i += 512) ((uint4*)wl)[i] = wsrc[sp * 1152 + i];
    __syncthreads();
    for (int s9 = 0; s9 < 9; ++s9) {
      const int dy = s9 / 3, dx = s9 % 3;
      bf16x8 a = *(const bf16x8*)&img[bl][2 * q3 + ry + dy][xi + dx][8 * lg];
#pragma unroll
      for (int tl = 0; tl < 2; ++tl) {
        bf16x8 bw = *(const bf16x8*)&wl[(s9 * 4 + lg) * 256 + (tl * 16 + ll) * 8];
        acc[tl] = mfma16(a, bw, acc[tl]);
      }
    }
  }
  float* P = P3 + (size_t)ics * 1048576;
  const int b = b0 + bl;
#pragma unroll
  for (int tl = 0; tl < 2; ++tl) {
#pragma unroll
    for (int r = 0; r < 4; ++r) {
      int px = 4 * lg + r;
      int yy = 2 * q3 + (px >> 3), xx = px & 7;
      P[((b * 8 + yy) * 8 + xx) * 128 + ocg * 32 + tl * 16 + ll] = acc[tl][r];
    }
  }
}

// ---------- conv3 reduce + LIF(0.1) + pool -> z3t bf16 [b][2048] (ref NCHW flatten) ----------
__global__ __launch_bounds__(256) void k_c3red(const float* __restrict__ P3,
    float* __restrict__ s3v, float* __restrict__ s3i, unsigned short* __restrict__ z3t)
{
  const int idx = blockIdx.x * 256 + threadIdx.x;  // 262144
  const int oc = idx & 127, ppx = (idx >> 7) & 3, py = (idx >> 9) & 3, b = idx >> 11;
  const float* P0 = P3;
  const float* P1 = P3 + 1048576;
  float zsum = 0.f;
#pragma unroll
  for (int r = 0; r < 2; ++r)
#pragma unroll
    for (int cc = 0; cc < 2; ++cc) {
      int si = ((b * 8 + 2 * py + r) * 8 + 2 * ppx + cc) * 128 + oc;
      float a = P0[si] + P1[si];
      float v = s3v[si], ii = s3i[si];
      zsum += lif1(a, 0.1f, v, ii);
      s3v[si] = v; s3i[si] = ii;
    }
  // reference flatten of (128,4,4): k = oc*16 + py*4 + ppx
  z3t[b * 2048 + oc * 16 + py * 4 + ppx] = f2bf(0.25f * zsum);
}

// ---------- fc1 (2048->1024) MFMA, K-split 8 -> P1[8][b 128][n 1024] ----------
// grid 512 = bb(2) x nb(32) x kb(8); 512 thr = 8 waves = 4 btiles x 2 ntiles
__global__ __launch_bounds__(512) void k_fc1(const unsigned short* __restrict__ z3t,
    const float* __restrict__ wf1, float* __restrict__ P1)
{
  const int bid = blockIdx.x;
  const int kb = bid & 7, nb = (bid >> 3) & 31, bb = bid >> 8;
  const int tid = threadIdx.x;
  __shared__ __align__(16) unsigned short slab[16384];  // [64 b][32 grp^swz][8]
  __shared__ __align__(16) unsigned short wl[8192];     // [ks 8][g 4][n 32][8]
  for (int gidx = tid; gidx < 2048; gidx += 512) {
    int row = gidx >> 5, gc = gidx & 31;
    const uint4* s = (const uint4*)(z3t + ((bb * 64 + row) * 2048 + kb * 256 + gc * 8));
    ((uint4*)slab)[row * 32 + (gc ^ (row & 7))] = *s;
  }
  const int w = tid >> 6, l = tid & 63;
  const int lg = l >> 4, ll = l & 15;
  const int bt = w >> 1, nt = w & 1;
  const int arow = bt * 16 + ll;
  f32x4 acc = {};
  for (int sp = 0; sp < 3; ++sp) {
    if (sp) __syncthreads();
    for (int idx = tid; idx < 8192; idx += 512) {
      int n = idx >> 8, k = idx & 255;
      float wv = wf1[(size_t)(nb * 32 + n) * 2048 + kb * 256 + k];
      int ks = k >> 5, g = (k >> 3) & 3, j = k & 7;
      wl[((ks * 4 + g) * 32 + n) * 8 + j] = split3(wv, sp);
    }
    __syncthreads();
#pragma unroll
    for (int ks = 0; ks < 8; ++ks) {
      bf16x8 a = *(const bf16x8*)&slab[(arow * 32 + ((ks * 4 + lg) ^ (arow & 7))) * 8];
      bf16x8 bw = *(const bf16x8*)&wl[((ks * 4 + lg) * 32 + nt * 16 + ll) * 8];
      acc = mfma16(a, bw, acc);
    }
  }
  const int bo = bb * 64 + bt * 16;
#pragma unroll
  for (int r = 0; r < 4; ++r)
    P1[(size_t)kb * 131072 + (bo + 4 * lg + r) * 1024 + nb * 32 + nt * 16 + ll] = acc[r];
}

// ---------- fc1 reduce + LIF(0.1) -> z4bf [b][1024] ----------
__global__ __launch_bounds__(256) void k_fc1b(const float* __restrict__ P1,
    float* __restrict__ s4v, float* __restrict__ s4i, unsigned short* __restrict__ z4bf)
{
  const int idx = blockIdx.x * 256 + threadIdx.x;  // 131072
  float a = 0.f;
#pragma unroll
  for (int kb = 0; kb < 8; ++kb) a += P1[(size_t)kb * 131072 + idx];
  float v = s4v[idx], ii = s4i[idx];
  float z = lif1(a, 0.1f, v, ii);
  s4v[idx] = v; s4i[idx] = ii;
  z4bf[idx] = f2bf(z);
}

// ---------- out layer (1024->10) + LI + running max ----------
// grid 32 x 256: wave per batch row
__global__ __launch_bounds__(256) void k_out(const unsigned short* __restrict__ z4bf,
    const float* __restrict__ wo, float* __restrict__ sov, float* __restrict__ soi,
    float* __restrict__ out, int t)
{
  const int w = threadIdx.x >> 6, l = threadIdx.x & 63;
  const int b = blockIdx.x * 4 + w;
  float a[10];
#pragma unroll
  for (int o = 0; o < 10; ++o) a[o] = 0.f;
#pragma unroll
  for (int c = 0; c < 2; ++c) {
    int k0 = c * 512 + l * 8;
    bf16x8 v8 = *(const bf16x8*)&z4bf[b * 1024 + k0];
    float zz[8];
#pragma unroll
    for (int e = 0; e < 8; ++e) zz[e] = bf2f((unsigned short)v8[e]);
#pragma unroll
    for (int o = 0; o < 10; ++o) {
      const float4 w0 = *(const float4*)&wo[o * 1024 + k0];
      const float4 w1 = *(const float4*)&wo[o * 1024 + k0 + 4];
      a[o] += zz[0]*w0.x + zz[1]*w0.y + zz[2]*w0.z + zz[3]*w0.w
            + zz[4]*w1.x + zz[5]*w1.y + zz[6]*w1.z + zz[7]*w1.w;
    }
  }
#pragma unroll
  for (int o = 0; o < 10; ++o)
#pragma unroll
    for (int d = 32; d > 0; d >>= 1) a[o] += __shfl_down(a[o], d);
  if (l == 0) {
#pragma unroll
    for (int o = 0; o < 10; ++o) {
      int si = b * 10 + o;
      float v = sov[si], ii = soi[si];
      float vn = fmaf(0.1f, ii - v, v);
      soi[si] = fmaf(0.8f, ii, a[o]);
      sov[si] = vn;
      float* op = out + b * 10 + o;
      if (t == 0) *op = vn; else *op = fmaxf(*op, vn);
    }
  }
}

extern "C" void kernel_launch(void* const* d_in, const int* in_sizes, int n_in,
                              void* d_out, int out_size, void* d_ws, size_t ws_size,
                              hipStream_t stream)
{
  const float* x   = (const float*)d_in[0];   // (16,128,3,32,32)
  const float* wc1 = (const float*)d_in[1];   // (32,3,3,3)
  const float* wc2 = (const float*)d_in[2];   // (64,32,3,3)
  const float* wc3 = (const float*)d_in[3];   // (128,64,3,3)
  const float* wf1 = (const float*)d_in[4];   // (1024,2048)
  const float* wo  = (const float*)d_in[5];   // (10,1024)
  float* out = (float*)d_out;                 // (128,10)
  char* ws = (char*)d_ws;

  // byte offsets
  float4* s1v = (float4*)(ws + 0);                         // (B,32,16,16) float4 sites
  float4* s1i = (float4*)(ws + 16777216);
  float* s2v  = (float*)(ws + 33554432);                   // (B,16,16,64)
  float* s2i  = (float*)(ws + 41943040);
  float* s3v  = (float*)(ws + 50331648);                   // (B,8,8,128)
  float* s3i  = (float*)(ws + 54525952);
  float* s4v  = (float*)(ws + 58720256);                   // (B,1024)
  float* s4i  = (float*)(ws + 59244544);
  float* sov  = (float*)(ws + 59768832);                   // (B,10)
  float* soi  = (float*)(ws + 59773952);
  unsigned short* z1bf = (unsigned short*)(ws + 59779072); // (B,16,16,32)
  unsigned short* z2bf = (unsigned short*)(ws + 61876224); // (B,8,8,64)
  unsigned short* z3t  = (unsigned short*)(ws + 62924800); // (B,2048)
  unsigned short* z4bf = (unsigned short*)(ws + 63449088); // (B,1024)
  float* P             = (float*)(ws + 63711232);          // 8.4MB: P3[2][..] / P1[8][..]
  unsigned short* wc2pk = (unsigned short*)(ws + 72099840); // 55296 sh = 110592 B
  unsigned short* wc3pk = (unsigned short*)(ws + 72210432); // 442368 sh = 884736 B
  // end 73,095,168 bytes

  k_pack2<<<216, 256, 0, stream>>>(wc2, wc2pk);
  k_pack3<<<1728, 256, 0, stream>>>(wc3, wc3pk);
  hipMemsetAsync(d_ws, 0, 59779072ull, stream);  // zero all persistent state

  for (int t = 0; t < 16; ++t) {
    const float* xt = x + (size_t)t * 393216;
    k_conv1<<<512, 256, 0, stream>>>(xt, wc1, s1v, s1i, z1bf);
    k_conv2<<<512, 512, 0, stream>>>(z1bf, wc2pk, s2v, s2i, z2bf);
    k_conv3<<<512, 512, 0, stream>>>(z2bf, wc3pk, P);
    k_c3red<<<1024, 256, 0, stream>>>(P, s3v, s3i, z3t);
    k_fc1 <<<512, 512, 0, stream>>>(z3t, wf1, P);
    k_fc1b<<<512, 256, 0, stream>>>(P, s4v, s4i, z4bf);
    k_out <<<32, 256, 0, stream>>>(z4bf, wo, sov, soi, out, t);
  }
}